// Round 4
// baseline (192.747 us; speedup 1.0000x reference)
//
#include <hip/hip_runtime.h>
#include <hip/hip_bf16.h>
#include <stdint.h>

#define B_DIM 8192
#define I_DIM 1024
#define H_DIM 1024
#define KTOT  2048
#define NTILES 32          // KTOT / 64

typedef __attribute__((ext_vector_type(8))) short short8;
typedef __attribute__((ext_vector_type(4))) float f32x4;

static __device__ __forceinline__ short f2b(float f) {
    __bf16 h = (__bf16)f;
    return __builtin_bit_cast(short, h);
}

static __device__ __forceinline__ short8 pack8(float4 a, float4 b) {
    short8 s;
    s[0] = f2b(a.x); s[1] = f2b(a.y); s[2] = f2b(a.z); s[3] = f2b(a.w);
    s[4] = f2b(b.x); s[5] = f2b(b.y); s[6] = f2b(b.z); s[7] = f2b(b.w);
    return s;
}

static __device__ __forceinline__ float sigmoid_f(float x) {
    return 1.0f / (1.0f + __expf(-x));
}

static __device__ __forceinline__ float tanh_fast(float x) {
    x = fminf(fmaxf(x, -15.0f), 15.0f);
    float e = __expf(2.0f * x);
    return (e - 1.0f) / (e + 1.0f);
}

static __device__ __forceinline__ void load_lds16(const void* gptr, void* lptr) {
    __builtin_amdgcn_global_load_lds(
        (const __attribute__((address_space(1))) uint32_t*)gptr,
        (__attribute__((address_space(3))) uint32_t*)lptr, 16, 0, 0);
}

// ---------------------------------------------------------------------------
// Pass 1: fp32 -> bf16 conversion into workspace (row-major).
//   A_ws [8192][2048]: k<1024 from x, k>=1024 from hprev
//   B_ws [4096][2048]: row n = gate*1024+h; k<1024 from Wx, k>=1024 from Wh
// ---------------------------------------------------------------------------
__global__ __launch_bounds__(256) void convert_kernel(
    const float* __restrict__ x, const float* __restrict__ h,
    const float* __restrict__ wx, const float* __restrict__ wh,
    short* __restrict__ Aw, short* __restrict__ Bw)
{
    const int64_t nx = (int64_t)B_DIM * I_DIM / 8;
    const int64_t nw = (int64_t)4 * H_DIM * I_DIM / 8;
    const int64_t total = 2 * nx + 2 * nw;
    for (int64_t g = (int64_t)blockIdx.x * blockDim.x + threadIdx.x; g < total;
         g += (int64_t)gridDim.x * blockDim.x) {
        const float* src;
        short* dst;
        if (g < nx) {
            int64_t r = g >> 7, kc = (g & 127) * 8;
            src = x + g * 8; dst = Aw + r * 2048 + kc;
        } else if (g < 2 * nx) {
            int64_t gg = g - nx;
            int64_t r = gg >> 7, kc = (gg & 127) * 8;
            src = h + gg * 8; dst = Aw + r * 2048 + 1024 + kc;
        } else if (g < 2 * nx + nw) {
            int64_t gg = g - 2 * nx;
            int64_t r = gg >> 7, kc = (gg & 127) * 8;
            src = wx + gg * 8; dst = Bw + r * 2048 + kc;
        } else {
            int64_t gg = g - 2 * nx - nw;
            int64_t r = gg >> 7, kc = (gg & 127) * 8;
            src = wh + gg * 8; dst = Bw + r * 2048 + 1024 + kc;
        }
        float4 v0 = ((const float4*)src)[0];
        float4 v1 = ((const float4*)src)[1];
        *(short8*)dst = pack8(v0, v1);
    }
}

// ---------------------------------------------------------------------------
// Pass 2: 256x256-tile GEMM, BK=64, ONE barrier per K-tile, compiler-scheduled
// interior (no asm lgkm waits / sched_barrier / setprio). Fragment-tile LDS
// (zero bank conflicts). Fused in-register LSTM epilogue.
// 512 threads = 8 waves (2 M x 4 N); per-wave output 128 x 64 (4 gates x 16 h).
// LDS 128 KiB: A[2 dbuf][2 khalf][16 fragtile][1 KiB], B likewise.
// ---------------------------------------------------------------------------

#define AOFF(d, kp, f) ((d) * 16384 + (kp) * 8192 + (f) * 512)
#define BOFF(d, kp, f) (32768 + (d) * 16384 + (kp) * 8192 + (f) * 512)

#define STAGE_A(dn, kh, tkp) \
    load_lds16(aSrc0 + (size_t)(tkp) * 64 + (kh) * 32, &smem[AOFF(dn, kh, 2 * w)]); \
    load_lds16(aSrc1 + (size_t)(tkp) * 64 + (kh) * 32, &smem[AOFF(dn, kh, 2 * w + 1)]);

#define STAGE_B(dn, kh, tkp) \
    load_lds16(bSrc0 + (size_t)(tkp) * 64 + (kh) * 32, &smem[BOFF(dn, kh, 2 * w)]); \
    load_lds16(bSrc1 + (size_t)(tkp) * 64 + (kh) * 32, &smem[BOFF(dn, kh, 2 * w + 1)]);

// One K-tile: stage next tile (8 gloads) first, then 24 ds_reads + 64 MFMA in
// plain program order (compiler interleaves lgkmcnt), then vmcnt(0)+barrier.
#define TILE(d, tn) do { \
    STAGE_A(d ^ 1, 0, tn) \
    STAGE_B(d ^ 1, 0, tn) \
    STAGE_A(d ^ 1, 1, tn) \
    STAGE_B(d ^ 1, 1, tn) \
    _Pragma("unroll") \
    for (int kp = 0; kp < 2; ++kp) { \
        short8 bv[4]; \
        _Pragma("unroll") \
        for (int j = 0; j < 4; ++j) \
            bv[j] = *(const short8*)&smem[BOFF(d, kp, wn * 4 + j) + lane * 8]; \
        short8 av[4]; \
        _Pragma("unroll") \
        for (int i = 0; i < 4; ++i) \
            av[i] = *(const short8*)&smem[AOFF(d, kp, wm * 8 + i) + lane * 8]; \
        _Pragma("unroll") \
        for (int i = 0; i < 4; ++i) \
            _Pragma("unroll") \
            for (int j = 0; j < 4; ++j) \
                acc[i][j] = __builtin_amdgcn_mfma_f32_16x16x32_bf16( \
                    av[i], bv[j], acc[i][j], 0, 0, 0); \
        short8 aw[4]; \
        _Pragma("unroll") \
        for (int i = 0; i < 4; ++i) \
            aw[i] = *(const short8*)&smem[AOFF(d, kp, wm * 8 + 4 + i) + lane * 8]; \
        _Pragma("unroll") \
        for (int i = 0; i < 4; ++i) \
            _Pragma("unroll") \
            for (int j = 0; j < 4; ++j) \
                acc[4 + i][j] = __builtin_amdgcn_mfma_f32_16x16x32_bf16( \
                    aw[i], bv[j], acc[4 + i][j], 0, 0, 0); \
    } \
    asm volatile("s_waitcnt vmcnt(0)" ::: "memory"); \
    __builtin_amdgcn_s_barrier(); \
} while (0)

__global__ __launch_bounds__(512, 2) void lstm_gemm8_kernel(
    const short* __restrict__ Aw, const short* __restrict__ Bw,
    const float* __restrict__ cprev, const float* __restrict__ bh,
    float* __restrict__ out)
{
    extern __shared__ __align__(16) short smem[];

    // XCD-aware swizzle: 512 blocks, 8 XCDs, bijective
    int bid = blockIdx.x;
    bid = (bid & 7) * 64 + (bid >> 3);
    const int bm = bid >> 4;     // 0..31  M-tile (256 rows)
    const int bn = bid & 15;     // 0..15  h-tile (64 h)
    const int m0 = bm * 256;
    const int h0 = bn * 64;

    const int t    = threadIdx.x;
    const int lane = t & 63;
    const int w    = t >> 6;     // wave 0..7
    const int wm   = w >> 2;     // 0..1
    const int wn   = w & 3;      // 0..3
    const int lc   = lane & 15;
    const int lk   = lane >> 4;  // k-slot 0..3

    // staging sources: wave w stages fragment-tiles f = 2w, 2w+1 of each half.
    const short* aSrc0 = Aw + (size_t)(m0 + (2 * w + 0) * 16 + lc) * 2048 + lk * 8;
    const short* aSrc1 = Aw + (size_t)(m0 + (2 * w + 1) * 16 + lc) * 2048 + lk * 8;
    const int cf0 = 2 * w, cf1 = 2 * w + 1;
    const short* bSrc0 = Bw + (size_t)((cf0 & 3) * 1024 + h0 + ((cf0 >> 2) << 4) + lc) * 2048 + lk * 8;
    const short* bSrc1 = Bw + (size_t)((cf1 & 3) * 1024 + h0 + ((cf1 >> 2) << 4) + lc) * 2048 + lk * 8;

    f32x4 acc[8][4] = {};   // [m-frag][gate]

    // prologue: stage tile 0 fully into dbuf 0
    STAGE_A(0, 0, 0)
    STAGE_B(0, 0, 0)
    STAGE_A(0, 1, 0)
    STAGE_B(0, 1, 0)
    asm volatile("s_waitcnt vmcnt(0)" ::: "memory");
    __builtin_amdgcn_s_barrier();

    #pragma unroll 1
    for (int tk2 = 0; tk2 < 16; ++tk2) {
        const int t1  = 2 * tk2 + 1;                     // tile for dbuf 1
        const int tp1 = (t1 + 1 < NTILES) ? t1 + 1 : t1; // prefetch for dbuf 0
        TILE(0, t1);
        TILE(1, tp1);
    }

    // ---- fused LSTM epilogue, in-register ----
    // D layout: col = lane&15 (h), row = (lane>>4)*4 + reg
    const int rg = lane >> 4;
    const int h  = h0 + wn * 16 + lc;
    const float b_i = bh[0 * H_DIM + h];
    const float b_f = bh[1 * H_DIM + h];
    const float b_g = bh[2 * H_DIM + h];
    const float b_o = bh[3 * H_DIM + h];

    #pragma unroll
    for (int mf = 0; mf < 8; ++mf) {
        #pragma unroll
        for (int r = 0; r < 4; ++r) {
            const int row = m0 + wm * 128 + mf * 16 + rg * 4 + r;
            const float pi = acc[mf][0][r] + b_i;
            const float pf = acc[mf][1][r] + b_f;
            const float pg = acc[mf][2][r] + b_g;
            const float po = acc[mf][3][r] + b_o;
            const float iv = sigmoid_f(pi);
            const float fv = sigmoid_f(pf);
            const float gv = tanh_fast(pg);
            const float ov = sigmoid_f(po);
            const float cp = cprev[(size_t)row * H_DIM + h];
            const float cn = fv * cp + iv * gv;
            const float hn = ov * tanh_fast(cn);
            out[(size_t)row * H_DIM + h] = hn;
            out[(size_t)B_DIM * H_DIM + (size_t)row * H_DIM + h] = cn;
        }
    }
}

// ---------------------------------------------------------------------------
// Fallback (no workspace) — kept for safety.
// ---------------------------------------------------------------------------
static __device__ __forceinline__ int swz(int row, int k) {
    int byte = (row << 7) + (k << 1);
    byte ^= (row & 7) << 4;
    return byte >> 1;
}

__global__ __launch_bounds__(256, 2) void lstm_fallback_kernel(
    const float* __restrict__ x, const float* __restrict__ hprev,
    const float* __restrict__ cprev, const float* __restrict__ Wx,
    const float* __restrict__ Wh, const float* __restrict__ bh,
    float* __restrict__ out)
{
    __shared__ __align__(16) short As[128 * 64];
    __shared__ __align__(16) short Bs[128 * 64];

    int bid = blockIdx.x;
    bid = (bid & 7) * 256 + (bid >> 3);
    const int mt = bid >> 5;
    const int ht = bid & 31;
    const int m0 = mt * 128;
    const int h0 = ht * 32;

    const int t    = threadIdx.x;
    const int lane = t & 63;
    const int w    = t >> 6;
    const int wr   = w >> 1;
    const int wc   = w & 1;

    const int srow = t >> 3;
    const int sk   = (t & 7) * 8;

    f32x4 acc[4][4] = {};

    #pragma unroll 1
    for (int phase = 0; phase < 2; ++phase) {
        const float* __restrict__ Ap = phase ? hprev : x;
        const float* __restrict__ Bp = phase ? Wh : Wx;
        #pragma unroll 1
        for (int kk = 0; kk < 1024; kk += 64) {
            __syncthreads();
            #pragma unroll
            for (int p = 0; p < 4; ++p) {
                const int row = srow + p * 32;
                const float4* src = (const float4*)(Ap + (size_t)(m0 + row) * I_DIM + kk + sk);
                *(short8*)&As[swz(row, sk)] = pack8(src[0], src[1]);
            }
            #pragma unroll
            for (int p = 0; p < 4; ++p) {
                const int n    = srow + p * 32;
                const int gate = (n >> 4) & 3;
                const int hcol = h0 + ((n >> 6) << 4) + (n & 15);
                const float4* src = (const float4*)(Bp + (size_t)((gate << 10) + hcol) * 1024 + kk + sk);
                *(short8*)&Bs[swz(n, sk)] = pack8(src[0], src[1]);
            }
            __syncthreads();
            #pragma unroll
            for (int ks = 0; ks < 2; ++ks) {
                const int kb = ks * 32 + ((lane >> 4) << 3);
                short8 a[4], b[4];
                #pragma unroll
                for (int m = 0; m < 4; ++m)
                    a[m] = *(const short8*)&As[swz(wr * 64 + m * 16 + (lane & 15), kb)];
                #pragma unroll
                for (int j = 0; j < 4; ++j)
                    b[j] = *(const short8*)&Bs[swz(wc * 64 + j * 16 + (lane & 15), kb)];
                #pragma unroll
                for (int m = 0; m < 4; ++m)
                    #pragma unroll
                    for (int j = 0; j < 4; ++j)
                        acc[m][j] = __builtin_amdgcn_mfma_f32_16x16x32_bf16(a[m], b[j], acc[m][j], 0, 0, 0);
            }
        }
    }

    const int cl = lane & 15;
    const int rg = lane >> 4;
    const int h  = h0 + wc * 16 + cl;
    const float b_i = bh[0 * H_DIM + h];
    const float b_f = bh[1 * H_DIM + h];
    const float b_g = bh[2 * H_DIM + h];
    const float b_o = bh[3 * H_DIM + h];

    #pragma unroll
    for (int m = 0; m < 4; ++m) {
        #pragma unroll
        for (int r = 0; r < 4; ++r) {
            const int row = m0 + wr * 64 + m * 16 + rg * 4 + r;
            const float pi = acc[m][0][r] + b_i;
            const float pf = acc[m][1][r] + b_f;
            const float pg = acc[m][2][r] + b_g;
            const float po = acc[m][3][r] + b_o;
            const float iv = sigmoid_f(pi);
            const float fv = sigmoid_f(pf);
            const float gv = tanh_fast(pg);
            const float ov = sigmoid_f(po);
            const float cp = cprev[(size_t)row * H_DIM + h];
            const float cn = fv * cp + iv * gv;
            const float hn = ov * tanh_fast(cn);
            out[(size_t)row * H_DIM + h] = hn;
            out[(size_t)B_DIM * H_DIM + (size_t)row * H_DIM + h] = cn;
        }
    }
}

extern "C" void kernel_launch(void* const* d_in, const int* in_sizes, int n_in,
                              void* d_out, int out_size, void* d_ws, size_t ws_size,
                              hipStream_t stream) {
    const float* x     = (const float*)d_in[0];
    const float* hprev = (const float*)d_in[1];
    const float* cprev = (const float*)d_in[2];
    const float* Wx    = (const float*)d_in[3];
    const float* Wh    = (const float*)d_in[4];
    const float* bh    = (const float*)d_in[5];
    float* out = (float*)d_out;

    const size_t need = ((size_t)B_DIM * 2048 + (size_t)4096 * 2048) * sizeof(short);
    if (ws_size >= need && d_ws != nullptr) {
        (void)hipFuncSetAttribute((const void*)lstm_gemm8_kernel,
                                  hipFuncAttributeMaxDynamicSharedMemorySize, 131072);
        short* Aw = (short*)d_ws;
        short* Bw = Aw + (size_t)B_DIM * 2048;
        hipLaunchKernelGGL(convert_kernel, dim3(2048), dim3(256), 0, stream,
                           x, hprev, Wx, Wh, Aw, Bw);
        hipLaunchKernelGGL(lstm_gemm8_kernel, dim3(512), dim3(512), 131072, stream,
                           Aw, Bw, cprev, bh, out);
    } else {
        hipLaunchKernelGGL(lstm_fallback_kernel, dim3(2048), dim3(256), 0, stream,
                           x, hprev, cprev, Wx, Wh, bh, out);
    }
}

// Round 5
// 174.684 us; speedup vs baseline: 1.1034x; 1.1034x over previous
//
#include <hip/hip_runtime.h>
#include <hip/hip_bf16.h>
#include <stdint.h>

#define B_DIM 8192
#define I_DIM 1024
#define H_DIM 1024
#define KTOT  2048
#define NTILES 32          // KTOT / 64

typedef __attribute__((ext_vector_type(8))) short short8;
typedef __attribute__((ext_vector_type(4))) float f32x4;

static __device__ __forceinline__ short f2b(float f) {
    __bf16 h = (__bf16)f;
    return __builtin_bit_cast(short, h);
}

static __device__ __forceinline__ short8 pack8(float4 a, float4 b) {
    short8 s;
    s[0] = f2b(a.x); s[1] = f2b(a.y); s[2] = f2b(a.z); s[3] = f2b(a.w);
    s[4] = f2b(b.x); s[5] = f2b(b.y); s[6] = f2b(b.z); s[7] = f2b(b.w);
    return s;
}

static __device__ __forceinline__ float sigmoid_f(float x) {
    return 1.0f / (1.0f + __expf(-x));
}

static __device__ __forceinline__ float tanh_fast(float x) {
    x = fminf(fmaxf(x, -15.0f), 15.0f);
    float e = __expf(2.0f * x);
    return (e - 1.0f) / (e + 1.0f);
}

static __device__ __forceinline__ void load_lds16(const void* gptr, void* lptr) {
    __builtin_amdgcn_global_load_lds(
        (const __attribute__((address_space(1))) uint32_t*)gptr,
        (__attribute__((address_space(3))) uint32_t*)lptr, 16, 0, 0);
}

// ---------------------------------------------------------------------------
// Pass 1: fp32 -> bf16 conversion into workspace (row-major).
//   A_ws [8192][2048]: k<1024 from x, k>=1024 from hprev
//   B_ws [4096][2048]: row n = gate*1024+h; k<1024 from Wx, k>=1024 from Wh
// ---------------------------------------------------------------------------
__global__ __launch_bounds__(256) void convert_kernel(
    const float* __restrict__ x, const float* __restrict__ h,
    const float* __restrict__ wx, const float* __restrict__ wh,
    short* __restrict__ Aw, short* __restrict__ Bw)
{
    const int64_t nx = (int64_t)B_DIM * I_DIM / 8;
    const int64_t nw = (int64_t)4 * H_DIM * I_DIM / 8;
    const int64_t total = 2 * nx + 2 * nw;
    for (int64_t g = (int64_t)blockIdx.x * blockDim.x + threadIdx.x; g < total;
         g += (int64_t)gridDim.x * blockDim.x) {
        const float* src;
        short* dst;
        if (g < nx) {
            int64_t r = g >> 7, kc = (g & 127) * 8;
            src = x + g * 8; dst = Aw + r * 2048 + kc;
        } else if (g < 2 * nx) {
            int64_t gg = g - nx;
            int64_t r = gg >> 7, kc = (gg & 127) * 8;
            src = h + gg * 8; dst = Aw + r * 2048 + 1024 + kc;
        } else if (g < 2 * nx + nw) {
            int64_t gg = g - 2 * nx;
            int64_t r = gg >> 7, kc = (gg & 127) * 8;
            src = wx + gg * 8; dst = Bw + r * 2048 + kc;
        } else {
            int64_t gg = g - 2 * nx - nw;
            int64_t r = gg >> 7, kc = (gg & 127) * 8;
            src = wh + gg * 8; dst = Bw + r * 2048 + 1024 + kc;
        }
        float4 v0 = ((const float4*)src)[0];
        float4 v1 = ((const float4*)src)[1];
        *(short8*)dst = pack8(v0, v1);
    }
}

// ---------------------------------------------------------------------------
// Pass 2: 256x256-tile 8-phase GEMM, BK=64, counted vmcnt, double-buffered
// FRAGMENT REGISTERS (consecutive phases use disjoint operand regs so the
// next phase's ds_reads don't WAR-stall against in-flight MFMAs).
// Fragment-tile LDS (zero bank conflicts). Fused in-register LSTM epilogue.
// 512 threads = 8 waves (2 M x 4 N); per-wave output 128 x 64 (4 gates x 16 h).
// LDS 128 KiB: A[2 dbuf][2 khalf][16 fragtile][1 KiB], B likewise.
// ---------------------------------------------------------------------------

#define AOFF(d, kp, f) ((d) * 16384 + (kp) * 8192 + (f) * 512)
#define BOFF(d, kp, f) (32768 + (d) * 16384 + (kp) * 8192 + (f) * 512)

#define STAGE_A(dn, kh, tkp) \
    load_lds16(aSrc0 + (size_t)(tkp) * 64 + (kh) * 32, &smem[AOFF(dn, kh, 2 * w)]); \
    load_lds16(aSrc1 + (size_t)(tkp) * 64 + (kh) * 32, &smem[AOFF(dn, kh, 2 * w + 1)]);

#define STAGE_B(dn, kh, tkp) \
    load_lds16(bSrc0 + (size_t)(tkp) * 64 + (kh) * 32, &smem[BOFF(dn, kh, 2 * w)]); \
    load_lds16(bSrc1 + (size_t)(tkp) * 64 + (kh) * 32, &smem[BOFF(dn, kh, 2 * w + 1)]);

#define VM4 asm volatile("s_waitcnt vmcnt(4)" ::: "memory");

// One phase: ds_reads into the phase-parity register buffer, stage-issue,
// barrier, MFMA cluster (compiler inserts precise lgkm waits), barrier.
#define PH(d, kp, mh, AV, BV, STAGE_STMT, EXTRAWAIT) do { \
    _Pragma("unroll") \
    for (int j = 0; j < 4; ++j) \
        BV[j] = *(const short8*)&smem[BOFF(d, kp, wn * 4 + j) + lane * 8]; \
    _Pragma("unroll") \
    for (int i = 0; i < 4; ++i) \
        AV[i] = *(const short8*)&smem[AOFF(d, kp, wm * 8 + (mh) * 4 + i) + lane * 8]; \
    STAGE_STMT \
    __builtin_amdgcn_s_barrier(); \
    __builtin_amdgcn_s_setprio(1); \
    _Pragma("unroll") \
    for (int i = 0; i < 4; ++i) \
        _Pragma("unroll") \
        for (int j = 0; j < 4; ++j) \
            acc[(mh) * 4 + i][j] = __builtin_amdgcn_mfma_f32_16x16x32_bf16( \
                AV[i], BV[j], acc[(mh) * 4 + i][j], 0, 0, 0); \
    __builtin_amdgcn_s_setprio(0); \
    EXTRAWAIT \
    __builtin_amdgcn_s_barrier(); \
} while (0)

#define TILE(d, tn) do { \
    PH(d, 0, 0, avA, bvA, STAGE_A(d ^ 1, 0, tn), ); \
    PH(d, 0, 1, avB, bvB, STAGE_B(d ^ 1, 0, tn), VM4); \
    PH(d, 1, 0, avA, bvA, STAGE_A(d ^ 1, 1, tn), ); \
    PH(d, 1, 1, avB, bvB, STAGE_B(d ^ 1, 1, tn), VM4); \
} while (0)

__global__ __launch_bounds__(512, 2) void lstm_gemm8_kernel(
    const short* __restrict__ Aw, const short* __restrict__ Bw,
    const float* __restrict__ cprev, const float* __restrict__ bh,
    float* __restrict__ out)
{
    extern __shared__ __align__(16) short smem[];

    // XCD-aware swizzle: 512 blocks, 8 XCDs, bijective
    int bid = blockIdx.x;
    bid = (bid & 7) * 64 + (bid >> 3);
    const int bm = bid >> 4;     // 0..31  M-tile (256 rows)
    const int bn = bid & 15;     // 0..15  h-tile (64 h)
    const int m0 = bm * 256;
    const int h0 = bn * 64;

    const int t    = threadIdx.x;
    const int lane = t & 63;
    const int w    = t >> 6;     // wave 0..7
    const int wm   = w >> 2;     // 0..1
    const int wn   = w & 3;      // 0..3
    const int lc   = lane & 15;
    const int lk   = lane >> 4;  // k-slot 0..3

    // staging sources: wave w stages fragment-tiles f = 2w, 2w+1 of each half.
    const short* aSrc0 = Aw + (size_t)(m0 + (2 * w + 0) * 16 + lc) * 2048 + lk * 8;
    const short* aSrc1 = Aw + (size_t)(m0 + (2 * w + 1) * 16 + lc) * 2048 + lk * 8;
    const int cf0 = 2 * w, cf1 = 2 * w + 1;
    const short* bSrc0 = Bw + (size_t)((cf0 & 3) * 1024 + h0 + ((cf0 >> 2) << 4) + lc) * 2048 + lk * 8;
    const short* bSrc1 = Bw + (size_t)((cf1 & 3) * 1024 + h0 + ((cf1 >> 2) << 4) + lc) * 2048 + lk * 8;

    f32x4 acc[8][4] = {};   // [m-frag][gate]
    short8 avA[4], avB[4], bvA[4], bvB[4];

    // prologue: stage tile 0 fully into dbuf 0, drain
    STAGE_A(0, 0, 0)
    STAGE_B(0, 0, 0)
    STAGE_A(0, 1, 0)
    STAGE_B(0, 1, 0)
    asm volatile("s_waitcnt vmcnt(0)" ::: "memory");
    __builtin_amdgcn_s_barrier();

    #pragma unroll 1
    for (int tk2 = 0; tk2 < 16; ++tk2) {
        const int t1  = 2 * tk2 + 1;                     // tile for dbuf 1
        const int tp1 = (t1 + 1 < NTILES) ? t1 + 1 : t1; // prefetch for dbuf 0
        TILE(0, t1);
        TILE(1, tp1);
    }
    asm volatile("s_waitcnt vmcnt(0)" ::: "memory");

    // ---- fused LSTM epilogue, in-register ----
    // D layout: col = lane&15 (h), row = (lane>>4)*4 + reg
    const int rg = lane >> 4;
    const int h  = h0 + wn * 16 + lc;
    const float b_i = bh[0 * H_DIM + h];
    const float b_f = bh[1 * H_DIM + h];
    const float b_g = bh[2 * H_DIM + h];
    const float b_o = bh[3 * H_DIM + h];

    #pragma unroll
    for (int mf = 0; mf < 8; ++mf) {
        #pragma unroll
        for (int r = 0; r < 4; ++r) {
            const int row = m0 + wm * 128 + mf * 16 + rg * 4 + r;
            const float pi = acc[mf][0][r] + b_i;
            const float pf = acc[mf][1][r] + b_f;
            const float pg = acc[mf][2][r] + b_g;
            const float po = acc[mf][3][r] + b_o;
            const float iv = sigmoid_f(pi);
            const float fv = sigmoid_f(pf);
            const float gv = tanh_fast(pg);
            const float ov = sigmoid_f(po);
            const float cp = cprev[(size_t)row * H_DIM + h];
            const float cn = fv * cp + iv * gv;
            const float hn = ov * tanh_fast(cn);
            out[(size_t)row * H_DIM + h] = hn;
            out[(size_t)B_DIM * H_DIM + (size_t)row * H_DIM + h] = cn;
        }
    }
}

// ---------------------------------------------------------------------------
// Fallback (no workspace) — kept for safety.
// ---------------------------------------------------------------------------
static __device__ __forceinline__ int swz(int row, int k) {
    int byte = (row << 7) + (k << 1);
    byte ^= (row & 7) << 4;
    return byte >> 1;
}

__global__ __launch_bounds__(256, 2) void lstm_fallback_kernel(
    const float* __restrict__ x, const float* __restrict__ hprev,
    const float* __restrict__ cprev, const float* __restrict__ Wx,
    const float* __restrict__ Wh, const float* __restrict__ bh,
    float* __restrict__ out)
{
    __shared__ __align__(16) short As[128 * 64];
    __shared__ __align__(16) short Bs[128 * 64];

    int bid = blockIdx.x;
    bid = (bid & 7) * 256 + (bid >> 3);
    const int mt = bid >> 5;
    const int ht = bid & 31;
    const int m0 = mt * 128;
    const int h0 = ht * 32;

    const int t    = threadIdx.x;
    const int lane = t & 63;
    const int w    = t >> 6;
    const int wr   = w >> 1;
    const int wc   = w & 1;

    const int srow = t >> 3;
    const int sk   = (t & 7) * 8;

    f32x4 acc[4][4] = {};

    #pragma unroll 1
    for (int phase = 0; phase < 2; ++phase) {
        const float* __restrict__ Ap = phase ? hprev : x;
        const float* __restrict__ Bp = phase ? Wh : Wx;
        #pragma unroll 1
        for (int kk = 0; kk < 1024; kk += 64) {
            __syncthreads();
            #pragma unroll
            for (int p = 0; p < 4; ++p) {
                const int row = srow + p * 32;
                const float4* src = (const float4*)(Ap + (size_t)(m0 + row) * I_DIM + kk + sk);
                *(short8*)&As[swz(row, sk)] = pack8(src[0], src[1]);
            }
            #pragma unroll
            for (int p = 0; p < 4; ++p) {
                const int n    = srow + p * 32;
                const int gate = (n >> 4) & 3;
                const int hcol = h0 + ((n >> 6) << 4) + (n & 15);
                const float4* src = (const float4*)(Bp + (size_t)((gate << 10) + hcol) * 1024 + kk + sk);
                *(short8*)&Bs[swz(n, sk)] = pack8(src[0], src[1]);
            }
            __syncthreads();
            #pragma unroll
            for (int ks = 0; ks < 2; ++ks) {
                const int kb = ks * 32 + ((lane >> 4) << 3);
                short8 a[4], b[4];
                #pragma unroll
                for (int m = 0; m < 4; ++m)
                    a[m] = *(const short8*)&As[swz(wr * 64 + m * 16 + (lane & 15), kb)];
                #pragma unroll
                for (int j = 0; j < 4; ++j)
                    b[j] = *(const short8*)&Bs[swz(wc * 64 + j * 16 + (lane & 15), kb)];
                #pragma unroll
                for (int m = 0; m < 4; ++m)
                    #pragma unroll
                    for (int j = 0; j < 4; ++j)
                        acc[m][j] = __builtin_amdgcn_mfma_f32_16x16x32_bf16(a[m], b[j], acc[m][j], 0, 0, 0);
            }
        }
    }

    const int cl = lane & 15;
    const int rg = lane >> 4;
    const int h  = h0 + wc * 16 + cl;
    const float b_i = bh[0 * H_DIM + h];
    const float b_f = bh[1 * H_DIM + h];
    const float b_g = bh[2 * H_DIM + h];
    const float b_o = bh[3 * H_DIM + h];

    #pragma unroll
    for (int m = 0; m < 4; ++m) {
        #pragma unroll
        for (int r = 0; r < 4; ++r) {
            const int row = m0 + wr * 64 + m * 16 + rg * 4 + r;
            const float pi = acc[m][0][r] + b_i;
            const float pf = acc[m][1][r] + b_f;
            const float pg = acc[m][2][r] + b_g;
            const float po = acc[m][3][r] + b_o;
            const float iv = sigmoid_f(pi);
            const float fv = sigmoid_f(pf);
            const float gv = tanh_fast(pg);
            const float ov = sigmoid_f(po);
            const float cp = cprev[(size_t)row * H_DIM + h];
            const float cn = fv * cp + iv * gv;
            const float hn = ov * tanh_fast(cn);
            out[(size_t)row * H_DIM + h] = hn;
            out[(size_t)B_DIM * H_DIM + (size_t)row * H_DIM + h] = cn;
        }
    }
}

extern "C" void kernel_launch(void* const* d_in, const int* in_sizes, int n_in,
                              void* d_out, int out_size, void* d_ws, size_t ws_size,
                              hipStream_t stream) {
    const float* x     = (const float*)d_in[0];
    const float* hprev = (const float*)d_in[1];
    const float* cprev = (const float*)d_in[2];
    const float* Wx    = (const float*)d_in[3];
    const float* Wh    = (const float*)d_in[4];
    const float* bh    = (const float*)d_in[5];
    float* out = (float*)d_out;

    const size_t need = ((size_t)B_DIM * 2048 + (size_t)4096 * 2048) * sizeof(short);
    if (ws_size >= need && d_ws != nullptr) {
        (void)hipFuncSetAttribute((const void*)lstm_gemm8_kernel,
                                  hipFuncAttributeMaxDynamicSharedMemorySize, 131072);
        short* Aw = (short*)d_ws;
        short* Bw = Aw + (size_t)B_DIM * 2048;
        hipLaunchKernelGGL(convert_kernel, dim3(2048), dim3(256), 0, stream,
                           x, hprev, Wx, Wh, Aw, Bw);
        hipLaunchKernelGGL(lstm_gemm8_kernel, dim3(512), dim3(512), 131072, stream,
                           Aw, Bw, cprev, bh, out);
    } else {
        hipLaunchKernelGGL(lstm_fallback_kernel, dim3(2048), dim3(256), 0, stream,
                           x, hprev, cprev, Wx, Wh, bh, out);
    }
}